// Round 8
// baseline (915.510 us; speedup 1.0000x reference)
//
#include <hip/hip_runtime.h>
#include <math.h>

#define GX 432
#define GY 496
#define NVOXEL (GX * GY)       // 214272 (grid z = 1)
#define MAX_PTS 32
#define MAX_VOX 80000
#define FEAT 11

typedef unsigned long long u64;
typedef unsigned int u32;

// Binning variant C: XLA-style. f32 subtract, then multiply by the
// compile-time f32 reciprocal of the voxel size (XLA AlgebraicSimplifier
// rewrites divide-by-constant to multiply-by-reciprocal in f32).
// 1/0.16f rounds to exactly 6.25f; 1/4.0f = 0.25f exact.
__device__ __forceinline__ int bin_lin(float4 p, bool* pvalid) {
    float sx = __fadd_rn(p.x, 0.0f);
    float sy = __fadd_rn(p.y, 39.68f);   // x - (-39.68f) == x + 39.68f (IEEE identical)
    float sz = __fadd_rn(p.z, 3.0f);
    float fx = __fmul_rn(sx, 6.25f);
    float fy = __fmul_rn(sy, 6.25f);
    float fz = __fmul_rn(sz, 0.25f);
    int cx = (int)floorf(fx);
    int cy = (int)floorf(fy);
    int cz = (int)floorf(fz);
    bool valid = (cx >= 0) && (cx < GX) && (cy >= 0) && (cy < GY) && (cz >= 0) && (cz < 1);
    *pvalid = valid;
    return valid ? (cx + GX * (cy + GY * cz)) : NVOXEL;
}

// ---------------- kernel 1: histogram + valid-count ----------------
__global__ void k_count(const float4* __restrict__ pts, int n,
                        int* __restrict__ count, int* __restrict__ diag) {
    int i = blockIdx.x * blockDim.x + threadIdx.x;
    bool valid = false;
    if (i < n) {
        int l = bin_lin(pts[i], &valid);
        if (valid) atomicAdd(&count[l], 1);
    }
    u64 m = __ballot(valid);
    if ((threadIdx.x & 63) == 0) atomicAdd(&diag[0], (int)__popcll(m));
}

// ---------------- single-block scan: packed (cumCount<<32 | cumOccupied) ----
#define SCAN_T 256
#define CHUNK 840   // 256*840 = 215040 >= 214272
__global__ void k_scan(const int* __restrict__ count, u64* __restrict__ scanpk) {
    __shared__ u64 lds[SCAN_T];
    int t = threadIdx.x;
    int base = t * CHUNK;
    u64 run = 0;
    for (int k = 0; k < CHUNK; ++k) {
        int idx = base + k;
        if (idx < NVOXEL) {
            int c = count[idx];
            run += ((u64)(u32)c << 32) | (u64)(c > 0 ? 1u : 0u);
        }
    }
    lds[t] = run;
    __syncthreads();
    for (int off = 1; off < SCAN_T; off <<= 1) {
        u64 x = (t >= off) ? lds[t - off] : 0;
        __syncthreads();
        lds[t] += x;
        __syncthreads();
    }
    u64 excl = (t > 0) ? lds[t - 1] : 0;
    run = excl;
    for (int k = 0; k < CHUNK; ++k) {
        int idx = base + k;
        if (idx < NVOXEL) {
            scanpk[idx] = run;   // exclusive: hi = segment start, lo = voxel rank
            int c = count[idx];
            run += ((u64)(u32)c << 32) | (u64)(c > 0 ? 1u : 0u);
        }
    }
    if (t == SCAN_T - 1) scanpk[NVOXEL] = run;   // grand totals
}

// ---------------- scatter point indices into segments (count reused as cursor)
__global__ void k_scatter(const float4* __restrict__ pts, int n,
                          const u64* __restrict__ scanpk,
                          int* __restrict__ cursor, int* __restrict__ sortedIdx) {
    int i = blockIdx.x * blockDim.x + threadIdx.x;
    if (i >= n) return;
    bool valid;
    int l = bin_lin(pts[i], &valid);
    if (!valid) return;
    int t = atomicAdd(&cursor[l], 1);
    int s = (int)(scanpk[l] >> 32);
    sortedIdx[s + t] = i;
}

// ---------------- rank -> voxel id map ----------------
__global__ void k_voxof(const int* __restrict__ count, const u64* __restrict__ scanpk,
                        int* __restrict__ voxOf) {
    int v = blockIdx.x * blockDim.x + threadIdx.x;
    if (v >= NVOXEL) return;
    if (count[v] > 0) {
        int r = (int)(scanpk[v] & 0xffffffffu);
        if (r < MAX_VOX) voxOf[r] = v;
    }
}

// ---------------- pillar features (one voxel per 64-lane wave), f32 out ----
__global__ void k_feats(const float4* __restrict__ pts, const int* __restrict__ count,
                        const u64* __restrict__ scanpk, const int* __restrict__ sortedIdx,
                        const int* __restrict__ voxOf, float* __restrict__ out) {
    int gt = blockIdx.x * blockDim.x + threadIdx.x;
    int r = gt >> 6;            // wave id == voxel rank
    int lane = threadIdx.x & 63;
    if (r >= MAX_VOX) return;

    int v = voxOf[r];
    bool has = (v >= 0);
    int cnt = 0, s = 0;
    int cx = 0, cy = 0, cz = 0;
    if (has) {
        cnt = count[v];
        s = (int)(scanpk[v] >> 32);
        cx = v % GX;
        cy = (v / GX) % GY;
        cz = v / (GX * GY);
    }

    // gather up to 64 point indices; sentinels unique and larger than any index
    int cc = cnt < 64 ? cnt : 64;
    int a = 0x40000000 + lane;
    if (lane < cc) a = sortedIdx[s + lane];

    // original-order rank within the wave (indices unique)
    int ra = 0;
    for (int j = 0; j < 64; ++j) {
        int aj = __shfl(a, j);
        ra += (aj < a) ? 1 : 0;
    }
    int myIdx = 0;
    for (int j = 0; j < 64; ++j) {
        int aj  = __shfl(a, j);
        int raj = __shfl(ra, j);
        if (raj == lane) myIdx = aj;
    }

    int n = cnt < MAX_PTS ? cnt : MAX_PTS;
    bool active = has && (lane < n);
    float4 pt = make_float4(0.f, 0.f, 0.f, 0.f);
    if (active) pt = pts[myIdx];

    // cluster mean over stored points
    float sx = active ? pt.x : 0.f;
    float sy = active ? pt.y : 0.f;
    float sz = active ? pt.z : 0.f;
    #pragma unroll
    for (int m = 32; m >= 1; m >>= 1) {
        sx += __shfl_xor(sx, m);
        sy += __shfl_xor(sy, m);
        sz += __shfl_xor(sz, m);
    }
    float nf = (float)(n > 0 ? n : 1);
    float mx = sx / nf, my = sy / nf, mz = sz / nf;

    const float XOFF = (float)(0.16 / 2.0 + 0.0);
    const float YOFF = (float)(0.16 / 2.0 - 39.68);
    const float ZOFF = (float)(4.0 / 2.0 - 3.0);
    float ctx = (float)cx * 0.16f + XOFF;
    float cty = (float)cy * 0.16f + YOFF;
    float ctz = (float)cz * 4.0f  + ZOFF;

    if (lane < MAX_PTS) {
        float f[FEAT];
        #pragma unroll
        for (int q = 0; q < FEAT; ++q) f[q] = 0.f;
        if (active) {
            f[0] = pt.x; f[1] = pt.y; f[2] = pt.z; f[3] = pt.w;
            f[4] = pt.x - mx; f[5] = pt.y - my; f[6] = pt.z - mz;
            f[7] = pt.x - ctx; f[8] = pt.y - cty; f[9] = pt.z - ctz;
            f[10] = sqrtf(pt.x * pt.x + pt.y * pt.y + pt.z * pt.z);
        }
        float* fo = out + ((size_t)r * MAX_PTS + lane) * FEAT;
        #pragma unroll
        for (int q = 0; q < FEAT; ++q) fo[q] = f[q];
    }

    if (lane == 0) {
        float* co = out + (size_t)MAX_VOX * MAX_PTS * FEAT + (size_t)r * 3;
        co[0] = (float)cz;   // (z, y, x); zeros when !has
        co[1] = (float)cy;
        co[2] = (float)cx;
    }
}

// ---------------- invariant beacons (fire only on failure) ----------------
__global__ void k_check2(const int* __restrict__ count, const u64* __restrict__ scanpk,
                         int* __restrict__ diag) {
    int v = blockIdx.x * blockDim.x + threadIdx.x;
    if (v >= NVOXEL) return;
    int c = count[v];
    int d = (int)((scanpk[v + 1] >> 32) - (scanpk[v] >> 32));
    if (c != d) atomicOr(&diag[1], 2);
    if (c > 64) atomicOr(&diag[1], 16);   // wave-sort capacity assumption
}
__global__ void k_check3(const int* __restrict__ voxOf, const u64* __restrict__ scanpk,
                         int* __restrict__ diag) {
    int r = blockIdx.x * blockDim.x + threadIdx.x;
    if (r >= MAX_VOX) return;
    int occ = (int)(scanpk[NVOXEL] & 0xffffffffu);
    if (r < occ && voxOf[r] < 0) atomicOr(&diag[1], 4);
}
__global__ void k_check4(const float4* __restrict__ pts, int n,
                         const int* __restrict__ sortedIdx,
                         const u64* __restrict__ scanpk, const int* __restrict__ count,
                         int* __restrict__ diag) {
    int i = blockIdx.x * blockDim.x + threadIdx.x;
    if (i >= n) return;
    int j = sortedIdx[i];
    if (j < 0 || j >= n) { atomicOr(&diag[1], 8); return; }
    bool valid;
    int l = bin_lin(pts[j], &valid);
    if (!valid) { atomicOr(&diag[1], 8); return; }
    int s = (int)(scanpk[l] >> 32);
    int c = count[l];
    if (i < s || i >= s + c) atomicOr(&diag[1], 8);
}
__global__ void k_beacon(const u64* __restrict__ scanpk, const int* __restrict__ diag,
                         float* __restrict__ out) {
    float add = 0.f;
    if (diag[0] != (int)(scanpk[NVOXEL] >> 32)) add += 1.0e6f;
    if (diag[1] & 2) add += 2.0e6f;
    if (diag[1] & 4) add += 4.0e6f;
    if (diag[1] & 8) add += 16.0e6f;
    if (diag[1] & 16) add += 32.0e6f;
    if (add != 0.f) out[0] = add;
}
__global__ void k_wsfail(float* __restrict__ out) { out[0] = 8.0e6f; }

// ---------------- launch ----------------
extern "C" void kernel_launch(void* const* d_in, const int* in_sizes, int n_in,
                              void* d_out, int out_size, void* d_ws, size_t ws_size,
                              hipStream_t stream) {
    const int N = in_sizes[0] / 4;                 // points: [N,4] f32
    const float4* pts = (const float4*)d_in[0];
    float* out = (float*)d_out;

    char* w = (char*)d_ws;
    size_t off = 0;
    int* sortedIdx = (int*)(w + off);  off += (size_t)N * 4;
    int* count = (int*)(w + off);      off += (size_t)NVOXEL * 4;
    off = (off + 15) & ~(size_t)15;
    u64* scanpk = (u64*)(w + off);     off += (size_t)(NVOXEL + 1) * 8;
    int* voxOf = (int*)(w + off);      off += (size_t)MAX_VOX * 4;
    int* diag = (int*)(w + off);       off += 16;
    const size_t need = off;

    if (ws_size < need || out_size != MAX_VOX * MAX_PTS * FEAT + MAX_VOX * 3) {
        k_wsfail<<<1, 1, 0, stream>>>(out);
        return;
    }

    hipMemsetAsync(count, 0, (size_t)NVOXEL * 4, stream);
    hipMemsetAsync(voxOf, 0xFF, (size_t)MAX_VOX * 4, stream);
    hipMemsetAsync(diag, 0, 16, stream);

    int nb_pts = (N + 255) / 256;
    k_count<<<nb_pts, 256, 0, stream>>>(pts, N, count, diag);

    k_scan<<<1, SCAN_T, 0, stream>>>(count, scanpk);

    // reuse count as cursor (ends up == count again after scatter)
    hipMemsetAsync(count, 0, (size_t)NVOXEL * 4, stream);
    k_scatter<<<nb_pts, 256, 0, stream>>>(pts, N, scanpk, count, sortedIdx);

    int nb_vox = (NVOXEL + 255) / 256;
    k_voxof<<<nb_vox, 256, 0, stream>>>(count, scanpk, voxOf);

    int nb_feat = (MAX_VOX * 64) / 256;   // one wave per voxel, exact
    k_feats<<<nb_feat, 256, 0, stream>>>(pts, count, scanpk, sortedIdx, voxOf, out);

    // invariant beacons (only touch out[0] on failure)
    k_check2<<<nb_vox, 256, 0, stream>>>(count, scanpk, diag);
    k_check3<<<(MAX_VOX + 255) / 256, 256, 0, stream>>>(voxOf, scanpk, diag);
    k_check4<<<nb_pts, 256, 0, stream>>>(pts, N, sortedIdx, scanpk, count, diag);
    k_beacon<<<1, 1, 0, stream>>>(scanpk, diag, out);
}

// Round 9
// 170.910 us; speedup vs baseline: 5.3567x; 5.3567x over previous
//
#include <hip/hip_runtime.h>
#include <math.h>

#define GX 432
#define GY 496
#define NVOXEL (GX * GY)       // 214272 (grid z = 1)
#define MAX_PTS 32
#define MAX_VOX 80000
#define FEAT 11

#define SCAN_B 256
#define SCAN_I 4
#define SCAN_TILE (SCAN_B * SCAN_I)   // 1024; nb1 = 210 blocks exactly

typedef unsigned long long u64;
typedef unsigned int u32;

// Binning (verified round 8): XLA-style f32 subtract then multiply by the
// compile-time f32 reciprocal (XLA canonicalizes /const to *recip).
// 1/0.16f == 6.25f exactly; 1/4.0f == 0.25f exactly.
__device__ __forceinline__ int bin_lin(float4 p, bool* pvalid) {
    float fx = __fmul_rn(__fadd_rn(p.x, 0.0f),   6.25f);
    float fy = __fmul_rn(__fadd_rn(p.y, 39.68f), 6.25f);
    float fz = __fmul_rn(__fadd_rn(p.z, 3.0f),   0.25f);
    int cx = (int)floorf(fx);
    int cy = (int)floorf(fy);
    int cz = (int)floorf(fz);
    bool valid = (cx >= 0) && (cx < GX) && (cy >= 0) && (cy < GY) && (cz >= 0) && (cz < 1);
    *pvalid = valid;
    return valid ? (cx + GX * (cy + GY * cz)) : NVOXEL;
}

// ---------------- kernel 1: histogram ----------------
__global__ void k_count(const float4* __restrict__ pts, int n,
                        int* __restrict__ count) {
    int i = blockIdx.x * blockDim.x + threadIdx.x;
    if (i >= n) return;
    bool valid;
    int l = bin_lin(pts[i], &valid);
    if (valid) atomicAdd(&count[l], 1);
}

// ---------------- hierarchical scan: packed (cumCount<<32 | cumOccupied) ----
__global__ void k_scan1(const int* __restrict__ count, u64* __restrict__ scanpk,
                        u64* __restrict__ bsums) {
    __shared__ u64 lds[SCAN_B];
    int t = threadIdx.x;
    int base = blockIdx.x * SCAN_TILE + t * SCAN_I;
    u64 pre[SCAN_I];
    u64 run = 0;
    #pragma unroll
    for (int k = 0; k < SCAN_I; ++k) {
        int idx = base + k;
        int c = (idx < NVOXEL) ? count[idx] : 0;
        pre[k] = run;
        run += ((u64)(u32)c << 32) | (u64)(c > 0 ? 1u : 0u);
    }
    lds[t] = run;
    __syncthreads();
    for (int off = 1; off < SCAN_B; off <<= 1) {
        u64 x = (t >= off) ? lds[t - off] : 0;
        __syncthreads();
        lds[t] += x;
        __syncthreads();
    }
    u64 excl = (t > 0) ? lds[t - 1] : 0;
    if (t == SCAN_B - 1) bsums[blockIdx.x] = lds[t];
    #pragma unroll
    for (int k = 0; k < SCAN_I; ++k) {
        int idx = base + k;
        if (idx < NVOXEL) scanpk[idx] = excl + pre[k];
    }
}

__global__ void k_scan2(u64* __restrict__ bsums, int nb) {
    __shared__ u64 lds[SCAN_B];
    int t = threadIdx.x;
    u64 x = (t < nb) ? bsums[t] : 0;
    lds[t] = x;
    __syncthreads();
    for (int off = 1; off < SCAN_B; off <<= 1) {
        u64 y = (t >= off) ? lds[t - off] : 0;
        __syncthreads();
        lds[t] += y;
        __syncthreads();
    }
    u64 excl = (t > 0) ? lds[t - 1] : 0;
    if (t < nb) bsums[t] = excl;
}

__global__ void k_scan3(u64* __restrict__ scanpk, const u64* __restrict__ bsums) {
    int t = threadIdx.x;
    int base = blockIdx.x * SCAN_TILE + t * SCAN_I;
    u64 add = bsums[blockIdx.x];
    #pragma unroll
    for (int k = 0; k < SCAN_I; ++k) {
        int idx = base + k;
        if (idx < NVOXEL) scanpk[idx] += add;
    }
}

// ---------------- scatter point indices into segments (count reused as cursor)
__global__ void k_scatter(const float4* __restrict__ pts, int n,
                          const u64* __restrict__ scanpk,
                          int* __restrict__ cursor, int* __restrict__ sortedIdx) {
    int i = blockIdx.x * blockDim.x + threadIdx.x;
    if (i >= n) return;
    bool valid;
    int l = bin_lin(pts[i], &valid);
    if (!valid) return;
    int t = atomicAdd(&cursor[l], 1);
    int s = (int)(scanpk[l] >> 32);
    sortedIdx[s + t] = i;
}

// ---------------- rank -> voxel id map ----------------
__global__ void k_voxof(const int* __restrict__ count, const u64* __restrict__ scanpk,
                        int* __restrict__ voxOf) {
    int v = blockIdx.x * blockDim.x + threadIdx.x;
    if (v >= NVOXEL) return;
    if (count[v] > 0) {
        int r = (int)(scanpk[v] & 0xffffffffu);
        if (r < MAX_VOX) voxOf[r] = v;
    }
}

// ---------------- pillar features (one voxel per 64-lane wave), f32 out ----
__global__ void k_feats(const float4* __restrict__ pts, const int* __restrict__ count,
                        const u64* __restrict__ scanpk, const int* __restrict__ sortedIdx,
                        const int* __restrict__ voxOf, float* __restrict__ out) {
    int gt = blockIdx.x * blockDim.x + threadIdx.x;
    int r = gt >> 6;            // wave id == voxel rank
    int lane = threadIdx.x & 63;
    if (r >= MAX_VOX) return;

    int v = voxOf[r];
    bool has = (v >= 0);
    int cnt = 0, s = 0;
    int cx = 0, cy = 0;
    if (has) {
        cnt = count[v];
        s = (int)(scanpk[v] >> 32);
        cx = v % GX;
        cy = v / GX;            // cz == 0 always (grid z = 1)
    }

    // gather up to 64 point indices; sentinels unique and larger than any index
    int cc = cnt < 64 ? cnt : 64;     // wave-uniform
    int a = 0x40000000 + lane;
    if (lane < cc) a = sortedIdx[s + lane];

    // rank among the cc real elements (loops are wave-uniform, ~6 avg iters)
    int ra = 0;
    for (int j = 0; j < cc; ++j) {
        int aj = __shfl(a, j);
        ra += (aj < a) ? 1 : 0;
    }
    int myIdx = -1;
    for (int j = 0; j < cc; ++j) {
        int aj  = __shfl(a, j);
        int raj = __shfl(ra, j);
        if (raj == lane) myIdx = aj;   // ranks of real elements unique in [0,cc)
    }

    int n = cnt < MAX_PTS ? cnt : MAX_PTS;
    bool active = has && (lane < n);
    float4 pt = make_float4(0.f, 0.f, 0.f, 0.f);
    if (active) pt = pts[myIdx];

    // cluster mean over stored points
    float sx = active ? pt.x : 0.f;
    float sy = active ? pt.y : 0.f;
    float sz = active ? pt.z : 0.f;
    #pragma unroll
    for (int m = 32; m >= 1; m >>= 1) {
        sx += __shfl_xor(sx, m);
        sy += __shfl_xor(sy, m);
        sz += __shfl_xor(sz, m);
    }
    float nf = (float)(n > 0 ? n : 1);
    float mx = sx / nf, my = sy / nf, mz = sz / nf;

    const float XOFF = (float)(0.16 / 2.0 + 0.0);
    const float YOFF = (float)(0.16 / 2.0 - 39.68);
    const float ZOFF = (float)(4.0 / 2.0 - 3.0);
    float ctx = (float)cx * 0.16f + XOFF;
    float cty = (float)cy * 0.16f + YOFF;
    float ctz = ZOFF;                  // cz == 0

    if (lane < MAX_PTS) {
        float f[FEAT];
        #pragma unroll
        for (int q = 0; q < FEAT; ++q) f[q] = 0.f;
        if (active) {
            f[0] = pt.x; f[1] = pt.y; f[2] = pt.z; f[3] = pt.w;
            f[4] = pt.x - mx; f[5] = pt.y - my; f[6] = pt.z - mz;
            f[7] = pt.x - ctx; f[8] = pt.y - cty; f[9] = pt.z - ctz;
            f[10] = sqrtf(pt.x * pt.x + pt.y * pt.y + pt.z * pt.z);
        }
        float* fo = out + ((size_t)r * MAX_PTS + lane) * FEAT;
        #pragma unroll
        for (int q = 0; q < FEAT; ++q) fo[q] = f[q];
    }

    if (lane == 0) {
        float* co = out + (size_t)MAX_VOX * MAX_PTS * FEAT + (size_t)r * 3;
        co[0] = 0.0f;              // z
        co[1] = (float)cy;
        co[2] = (float)cx;
    }
}

__global__ void k_wsfail(float* __restrict__ out) { out[0] = 8.0e6f; }

// ---------------- launch ----------------
extern "C" void kernel_launch(void* const* d_in, const int* in_sizes, int n_in,
                              void* d_out, int out_size, void* d_ws, size_t ws_size,
                              hipStream_t stream) {
    const int N = in_sizes[0] / 4;                 // points: [N,4] f32
    const float4* pts = (const float4*)d_in[0];
    float* out = (float*)d_out;

    char* w = (char*)d_ws;
    size_t off = 0;
    int* sortedIdx = (int*)(w + off);  off += (size_t)N * 4;
    int* count = (int*)(w + off);      off += (size_t)NVOXEL * 4;
    off = (off + 15) & ~(size_t)15;
    u64* scanpk = (u64*)(w + off);     off += (size_t)NVOXEL * 8;
    u64* bsums = (u64*)(w + off);      off += 256 * 8;
    int* voxOf = (int*)(w + off);      off += (size_t)MAX_VOX * 4;
    const size_t need = off;

    if (ws_size < need || out_size != MAX_VOX * MAX_PTS * FEAT + MAX_VOX * 3) {
        k_wsfail<<<1, 1, 0, stream>>>(out);
        return;
    }

    hipMemsetAsync(count, 0, (size_t)NVOXEL * 4, stream);
    hipMemsetAsync(voxOf, 0xFF, (size_t)MAX_VOX * 4, stream);

    int nb_pts = (N + 255) / 256;
    k_count<<<nb_pts, 256, 0, stream>>>(pts, N, count);

    int nb1 = (NVOXEL + SCAN_TILE - 1) / SCAN_TILE;   // 210
    k_scan1<<<nb1, SCAN_B, 0, stream>>>(count, scanpk, bsums);
    k_scan2<<<1, SCAN_B, 0, stream>>>(bsums, nb1);
    k_scan3<<<nb1, SCAN_B, 0, stream>>>(scanpk, bsums);

    // reuse count as cursor (ends up == count again after scatter)
    hipMemsetAsync(count, 0, (size_t)NVOXEL * 4, stream);
    k_scatter<<<nb_pts, 256, 0, stream>>>(pts, N, scanpk, count, sortedIdx);

    int nb_vox = (NVOXEL + 255) / 256;
    k_voxof<<<nb_vox, 256, 0, stream>>>(count, scanpk, voxOf);

    int nb_feat = (MAX_VOX * 64) / 256;   // one wave per voxel, exact
    k_feats<<<nb_feat, 256, 0, stream>>>(pts, count, scanpk, sortedIdx, voxOf, out);
}